// Round 13
// baseline (230.321 us; speedup 1.0000x reference)
//
#include <hip/hip_runtime.h>
#include <hip/hip_fp16.h>

#define C 128
#define NEG_SLOPE 0.2f
#define SM_EPS 1e-16f
#define BKT_SHIFT 6            // 64 nodes per bucket (build parallelism @256thr)
#define BKT_MASK 63
#define NBPAD 784              // padded bucket-count stride for H rows
#define WP 136                 // LDS pitch (u16) for h-writeback slice

typedef unsigned int uint32;
typedef __attribute__((ext_vector_type(8))) short bf16x8;
typedef __attribute__((ext_vector_type(4))) float f32x4;

// ---- bf16 helpers (RNE) ----
static __device__ __forceinline__ unsigned short f2bf(float f) {
    uint32 u = __float_as_uint(f);
    uint32 r = 0x7FFFu + ((u >> 16) & 1u);
    return (unsigned short)((u + r) >> 16);
}
static __device__ __forceinline__ uint32 f2bf2(float lo, float hi) {
    return (uint32)f2bf(lo) | ((uint32)f2bf(hi) << 16);
}
// ---- f16 bit helpers ----
static __device__ __forceinline__ uint32 f2h(float f) {
    __half h = __float2half(f);
    return (uint32)*reinterpret_cast<unsigned short*>(&h);
}
static __device__ __forceinline__ float h2f(uint32 b) {
    unsigned short s = (unsigned short)(b & 0xffffu);
    __half h = *reinterpret_cast<__half*>(&s);
    return __half2float(h);
}

// ---- shared GEMM tile body (64 rows, 256 threads); h only, no alphas ----
static __device__ __forceinline__ void gemm_tile_body(
    const float* __restrict__ x, const uint32* __restrict__ Wf,
    unsigned short* __restrict__ hb, int N, int tile, char* smem)
{
    typedef unsigned short SliceRow[16 * WP];
    SliceRow* slice = (SliceRow*)smem;
    const int tid  = threadIdx.x;
    const int lane = tid & 63;
    const int w    = tid >> 6;
    const int row0 = tile * 64;
    const int m16  = lane & 15;
    const int q    = lane >> 4;

    const int row = row0 + w * 16 + m16;
    const bool rv = (row < N);
    const float* xr_p = x + (size_t)(rv ? row : 0) * C + q * 8;

    float4 xr[8];
    #pragma unroll
    for (int kk = 0; kk < 4; ++kk) {
        xr[kk * 2]     = rv ? *(const float4*)(xr_p + kk * 32)     : make_float4(0, 0, 0, 0);
        xr[kk * 2 + 1] = rv ? *(const float4*)(xr_p + kk * 32 + 4) : make_float4(0, 0, 0, 0);
    }

    f32x4 acc[8];
    const f32x4 zz = {0.f, 0.f, 0.f, 0.f};
    #pragma unroll
    for (int t = 0; t < 8; ++t) acc[t] = zz;

    #pragma unroll
    for (int kk = 0; kk < 4; ++kk) {
        union { bf16x8 v; uint32 u[4]; } au;
        float4 p0 = xr[kk * 2], p1 = xr[kk * 2 + 1];
        au.u[0] = f2bf2(p0.x, p0.y); au.u[1] = f2bf2(p0.z, p0.w);
        au.u[2] = f2bf2(p1.x, p1.y); au.u[3] = f2bf2(p1.z, p1.w);
        #pragma unroll
        for (int t = 0; t < 8; ++t) {
            bf16x8 b = *(const bf16x8*)&Wf[((t * 4 + kk) * 64 + lane) * 4];
            acc[t] = __builtin_amdgcn_mfma_f32_16x16x32_bf16(au.v, b, acc[t], 0, 0, 0);
        }
    }

    #pragma unroll
    for (int t = 0; t < 8; ++t)
        #pragma unroll
        for (int r = 0; r < 4; ++r)
            slice[w][(q * 4 + r) * WP + t * 16 + m16] = f2bf(acc[t][r]);
    __syncthreads();
    #pragma unroll
    for (int it = 0; it < 4; ++it) {
        int r = it * 4 + q;
        int rr = row0 + w * 16 + r;
        if (rr < N) {
            bf16x8 v = *(const bf16x8*)&slice[w][r * WP + m16 * 8];
            *(bf16x8*)&hb[(size_t)rr * C + m16 * 8] = v;
        }
    }
}

// ---- k1: W conv + wa=W@a matvec (block 32) + per-chunk bucket hist ----
__global__ __launch_bounds__(256) void cvtw_hist_kernel(
    const float* __restrict__ W, uint32* __restrict__ Wf,
    const float* __restrict__ a_src, const float* __restrict__ a_dst,
    float* __restrict__ wa_s, float* __restrict__ wa_d,
    const int* __restrict__ dst, int* __restrict__ H,
    int E, int total, int NB, int chunkE)
{
    __shared__ int lhist[NBPAD];
    __shared__ float asd[256];
    const int tid = threadIdx.x;
    for (int i = tid; i < NBPAD; i += 256) lhist[i] = 0;
    const int gid = blockIdx.x * 256 + tid;
    if (gid < 8192) {
        int j2   = gid & 3;
        int lane = (gid >> 2) & 63;
        int tile = gid >> 8;
        int t = tile >> 2, kk = tile & 3;
        int n = t * 16 + (lane & 15);
        int k = kk * 32 + (lane >> 4) * 8 + j2 * 2;
        Wf[gid] = f2bf2(W[k * C + n], W[(k + 1) * C + n]);
    }
    if (blockIdx.x == 32) {
        asd[tid] = (tid < 128) ? a_src[tid] : a_dst[tid - 128];
        __syncthreads();
        const float* wrow = W + (size_t)(tid & 127) * C;
        float acc = 0.f;
        if (tid < 128) {
            #pragma unroll 4
            for (int j = 0; j < 128; ++j) acc += wrow[j] * asd[j];
            wa_s[tid] = acc;
        } else {
            #pragma unroll 4
            for (int j = 0; j < 128; ++j) acc += wrow[j] * asd[128 + j];
            wa_d[tid - 128] = acc;
        }
    }
    __syncthreads();
    const int c = blockIdx.x;
    if (c >= NB) return;
    const int start = c * chunkE;
    const int end = min(start + chunkE, total);
    for (int i = start + tid; i < end; i += 256) {
        int d = (i < E) ? dst[i] : (i - E);
        atomicAdd(&lhist[d >> BKT_SHIFT], 1);
    }
    __syncthreads();
    for (int b = tid; b < NBPAD; b += 256) H[c * NBPAD + b] = lhist[b];
}

// ---- k2: role-split — column scans of H (blocks < NB) || alpha matvec ----
__global__ __launch_bounds__(1024) void scan_alpha_kernel(
    int* __restrict__ H, int* __restrict__ colTot,
    const float* __restrict__ x, const float* __restrict__ wa_s,
    const float* __restrict__ wa_d, float* __restrict__ as,
    float* __restrict__ ad, int NB, int N)
{
    __shared__ int wt[16];
    __shared__ float wls[128], wld[128];
    const int tid  = threadIdx.x;
    if (blockIdx.x < (unsigned)NB) {
        const int lane = tid & 63;
        const int w    = tid >> 6;
        const int col  = blockIdx.x;
        int v = (tid < NB) ? H[tid * NBPAD + col] : 0;   // nchunk == NB
        int x2 = v;
        #pragma unroll
        for (int o = 1; o < 64; o <<= 1) {
            int t = __shfl_up(x2, o, 64);
            if (lane >= o) x2 += t;
        }
        if (lane == 63) wt[w] = x2;
        __syncthreads();
        int wbase = 0;
        #pragma unroll
        for (int w2 = 0; w2 < 16; ++w2) wbase += (w2 < w) ? wt[w2] : 0;
        int e = wbase + x2 - v;
        if (tid < NB) H[tid * NBPAD + col] = e;
        if (tid == NB - 1) colTot[col] = e + v;
    } else {
        if (tid < 128) wls[tid] = wa_s[tid];
        else if (tid < 256) wld[tid - 128] = wa_d[tid - 128];
        __syncthreads();
        const int r = (blockIdx.x - NB) * 1024 + tid;
        if (r < N) {
            const float4* xr = (const float4*)(x + (size_t)r * C);
            float s1 = 0.f, s2 = 0.f;
            #pragma unroll 8
            for (int j = 0; j < 32; ++j) {
                float4 xv = xr[j];
                float4 a = *(const float4*)&wls[j * 4];
                float4 b = *(const float4*)&wld[j * 4];
                s1 += xv.x * a.x + xv.y * a.y + xv.z * a.z + xv.w * a.w;
                s2 += xv.x * b.x + xv.y * b.y + xv.z * b.z + xv.w * b.w;
            }
            as[r] = s1;
            ad[r] = s2;
        }
    }
}

// ---- k2.5: one-block scan of colTot -> bucket_off[0..NB] ----
__global__ __launch_bounds__(1024) void scan_off_kernel(
    const int* __restrict__ colTot, int* __restrict__ bucket_off, int NB)
{
    __shared__ int wt[16];
    const int tid  = threadIdx.x;
    const int lane = tid & 63;
    const int w    = tid >> 6;
    int v = (tid < NB) ? colTot[tid] : 0;
    int x = v;
    #pragma unroll
    for (int o = 1; o < 64; o <<= 1) {
        int t = __shfl_up(x, o, 64);
        if (lane >= o) x += t;
    }
    if (lane == 63) wt[w] = x;
    __syncthreads();
    int wbase = 0;
    #pragma unroll
    for (int w2 = 0; w2 < 16; ++w2) wbase += (w2 < w) ? wt[w2] : 0;
    if (tid <= NB) bucket_off[tid] = wbase + x - v;   // tid==NB -> total
}

// ---- k3: role-split — GEMM tiles [0,nG1) || bin chunks ----
__global__ __launch_bounds__(256) void gemm_bin_kernel(
    const float* __restrict__ x, const uint32* __restrict__ Wf,
    unsigned short* __restrict__ hb, int N,
    const int* __restrict__ src, const int* __restrict__ dst,
    const int* __restrict__ bucket_off, const int* __restrict__ H,
    uint32* __restrict__ packed, int E, int total, int nG1, int NB, int chunkE)
{
    __shared__ __align__(16) char smem[17408];
    const int tid = threadIdx.x;
    if (blockIdx.x < (unsigned)nG1) {
        gemm_tile_body(x, Wf, hb, N, blockIdx.x, smem);
    } else {
        int* lhist = (int*)smem;          // NBPAD ints
        int* base  = lhist + NBPAD;       // NBPAD ints (12.5KB total < 17.4KB)
        const int c = blockIdx.x - nG1;
        for (int b = tid; b < NB; b += 256) {
            lhist[b] = 0;
            base[b] = bucket_off[b] + H[c * NBPAD + b];
        }
        __syncthreads();
        const int start = c * chunkE;
        const int end = min(start + chunkE, total);
        for (int i = start + tid; i < end; i += 256) {
            int s = (i < E) ? src[i] : (i - E);
            int d = (i < E) ? dst[i] : (i - E);
            int b = d >> BKT_SHIFT;
            int pos = base[b] + atomicAdd(&lhist[b], 1);
            packed[pos] = ((uint32)s << BKT_SHIFT) | (uint32)(d & BKT_MASK);
        }
    }
}

// ---- k4: role-split — build buckets [0,NB) || GEMM tiles [nG1,ntile) ----
__global__ __launch_bounds__(256) void build_gemm_kernel(
    const float* __restrict__ x, const uint32* __restrict__ Wf,
    unsigned short* __restrict__ hb, int N,
    const uint32* __restrict__ packed, const int* __restrict__ bucket_off,
    const float* __restrict__ as, const float* __restrict__ ad,
    int* __restrict__ row_start, uint32* __restrict__ csr,
    int total, int nG1, int NB)
{
    __shared__ __align__(16) char smem[17408];
    const int tid = threadIdx.x;
    if (blockIdx.x >= (unsigned)NB) {
        gemm_tile_body(x, Wf, hb, N, nG1 + (blockIdx.x - NB), smem);
    } else {
        int* cnt   = (int*)smem;              // 64
        int* cur   = cnt + 64;                // 64
        float* adl = (float*)(cur + 64);      // 64
        const int b = blockIdx.x;
        const int off = bucket_off[b];
        const int end = bucket_off[b + 1];
        if (tid < 64) {
            cnt[tid] = 0;
            int g = (b << BKT_SHIFT) + tid;
            adl[tid] = (g < N) ? ad[g] : 0.f;
        }
        if (b == 0 && tid == 0) row_start[N] = total;
        __syncthreads();
        for (int j = off + tid; j < end; j += 256)
            atomicAdd(&cnt[packed[j] & BKT_MASK], 1);
        __syncthreads();
        if (tid < 64) {                      // wave 0: 64-wide exclusive scan
            int v = cnt[tid];
            int x2 = v;
            #pragma unroll
            for (int o = 1; o < 64; o <<= 1) {
                int t = __shfl_up(x2, o, 64);
                if (tid >= o) x2 += t;
            }
            int excl = x2 - v;
            int g = (b << BKT_SHIFT) + tid;
            if (g < N) row_start[g] = off + excl;
            cur[tid] = excl;
        }
        __syncthreads();
        for (int j = off + tid; j < end; j += 256) {
            uint32 p = packed[j];
            int l = (int)(p & BKT_MASK);
            int s = (int)(p >> BKT_SHIFT);
            float e = as[s] + adl[l];
            e = (e > 0.f) ? e : NEG_SLOPE * e;
            int pos = atomicAdd(&cur[l], 1);
            csr[off + pos] = ((uint32)s << 16) | f2h(e);
        }
    }
}

// ---- full-wave fallback for deg>64 nodes ----
static __device__ __forceinline__ void gather_node_fw(
    int d, const uint32* __restrict__ csr, const int* __restrict__ row_start,
    const unsigned short* __restrict__ hb, const float* __restrict__ bias,
    float* __restrict__ out, int lane)
{
    const int beg = row_start[d];
    const int deg = row_start[d + 1] - beg;
    const int c2 = lane << 1;
    float a0 = 0.f, a1 = 0.f;
    float m = -INFINITY;
    for (int t = lane; t < deg; t += 64) m = fmaxf(m, h2f(csr[beg + t]));
    #pragma unroll
    for (int off = 32; off > 0; off >>= 1) m = fmaxf(m, __shfl_xor(m, off, 64));
    float ssum = 0.f;
    for (int t = lane; t < deg; t += 64) ssum += __expf(h2f(csr[beg + t]) - m);
    #pragma unroll
    for (int off = 32; off > 0; off >>= 1) ssum += __shfl_xor(ssum, off, 64);
    float inv = 1.f / (ssum + SM_EPS);
    for (int t0 = 0; t0 < deg; t0 += 64) {
        int nc = min(64, deg - t0);
        uint32 ent = (lane < nc) ? csr[beg + t0 + lane] : 0xFC00u;
        float wl = (lane < nc) ? __expf(h2f(ent) - m) * inv : 0.f;
        uint32 bc = (ent & 0xffff0000u) | f2h(wl);
        for (int t = 0; t < nc; ++t) {
            uint32 b0 = (uint32)__shfl((int)bc, t, 64);
            uint32 u0 = *(const uint32*)&hb[(size_t)(b0 >> 16) * C + c2];
            float w0 = h2f(b0);
            a0 += __uint_as_float(u0 << 16) * w0;
            a1 += __uint_as_float(u0 & 0xffff0000u) * w0;
        }
    }
    float2 b2 = *(const float2*)&bias[c2];
    a0 = fmaxf(a0 + b2.x, 0.f);
    a1 = fmaxf(a1 + b2.y, 0.f);
    *(float2*)&out[(size_t)d * C + c2] = make_float2(a0, a1);
}

// per-edge unpack+FMA on a loaded uint2 row fragment (4 bf16 channels)
#define ACC4(r, wgt)                                           \
    {                                                          \
        a0 += __uint_as_float((r).x << 16)         * (wgt);    \
        a1 += __uint_as_float((r).x & 0xffff0000u) * (wgt);    \
        a2 += __uint_as_float((r).y << 16)         * (wgt);    \
        a3 += __uint_as_float((r).y & 0xffff0000u) * (wgt);    \
    }

// ---- k5: half-wave gather: 2 dst nodes per wave, 4 ch/lane, MLP=8 ----
__global__ __launch_bounds__(256) void gather_kernel(
    const uint32* __restrict__ csr, const int* __restrict__ row_start,
    const unsigned short* __restrict__ hb, const float* __restrict__ bias,
    float* __restrict__ out, int N)
{
    __shared__ __align__(16) uint2 lent[4][2][64];   // 4 KB: per-wave, per-half
    const int w    = threadIdx.x >> 6;
    const int lane = threadIdx.x & 63;
    const int half = lane >> 5;
    const int hl   = lane & 31;
    const int pair = blockIdx.x * 4 + w;
    const int d0 = pair * 2;
    if (d0 >= N) return;                    // no barriers below: safe
    const int d = d0 + half;
    const bool valid = (d < N);

    int beg = 0, deg = 0;
    if (valid) { beg = row_start[d]; deg = row_start[d + 1] - beg; }

    int wdeg = deg;
    #pragma unroll
    for (int off = 32; off > 0; off >>= 1) wdeg = max(wdeg, __shfl_xor(wdeg, off, 64));

    if (wdeg > 64) {
        gather_node_fw(d0, csr, row_start, hb, bias, out, lane);
        if (d0 + 1 < N) gather_node_fw(d0 + 1, csr, row_start, hb, bias, out, lane);
        return;
    }

    uint32 ent0 = (hl < deg) ? csr[beg + hl] : 0xFC00u;
    uint32 ent1 = (32 + hl < deg) ? csr[beg + 32 + hl] : 0xFC00u;
    float e0 = h2f(ent0), e1 = h2f(ent1);
    float m = fmaxf(e0, e1);
    #pragma unroll
    for (int off = 16; off > 0; off >>= 1) m = fmaxf(m, __shfl_xor(m, off, 64));
    float p0 = (hl < deg) ? __expf(e0 - m) : 0.f;
    float p1 = (32 + hl < deg) ? __expf(e1 - m) : 0.f;
    float ssum = p0 + p1;
    #pragma unroll
    for (int off = 16; off > 0; off >>= 1) ssum += __shfl_xor(ssum, off, 64);
    const float inv = 1.f / (ssum + SM_EPS);

    // stage {row byte offset = src*256, f32 weight} — wave-synchronous LDS
    lent[w][half][hl]      = make_uint2((ent0 & 0xffff0000u) >> 8, __float_as_uint(p0 * inv));
    lent[w][half][32 + hl] = make_uint2((ent1 & 0xffff0000u) >> 8, __float_as_uint(p1 * inv));
    __builtin_amdgcn_wave_barrier();        // keep writes before reads (same wave)

    const uint32 cb = (uint32)(hl << 3);    // this lane's channel byte offset
    const char* hbB = (const char*)hb;
    const uint2* lp = &lent[w][half][0];
    float a0 = 0.f, a1 = 0.f, a2 = 0.f, a3 = 0.f;

    int t = 0;
    for (; t + 8 <= deg; t += 8) {
        uint4 q0 = *(const uint4*)(lp + t);
        uint4 q1 = *(const uint4*)(lp + t + 2);
        uint4 q2 = *(const uint4*)(lp + t + 4);
        uint4 q3 = *(const uint4*)(lp + t + 6);
        uint2 r0 = *(const uint2*)(hbB + (q0.x + cb));
        uint2 r1 = *(const uint2*)(hbB + (q0.z + cb));
        uint2 r2 = *(const uint2*)(hbB + (q1.x + cb));
        uint2 r3 = *(const uint2*)(hbB + (q1.z + cb));
        uint2 r4 = *(const uint2*)(hbB + (q2.x + cb));
        uint2 r5 = *(const uint2*)(hbB + (q2.z + cb));
        uint2 r6 = *(const uint2*)(hbB + (q3.x + cb));
        uint2 r7 = *(const uint2*)(hbB + (q3.z + cb));
        float w0 = __uint_as_float(q0.y), w1 = __uint_as_float(q0.w);
        float w2 = __uint_as_float(q1.y), w3 = __uint_as_float(q1.w);
        float w4 = __uint_as_float(q2.y), w5 = __uint_as_float(q2.w);
        float w6 = __uint_as_float(q3.y), w7 = __uint_as_float(q3.w);
        ACC4(r0, w0) ACC4(r1, w1) ACC4(r2, w2) ACC4(r3, w3)
        ACC4(r4, w4) ACC4(r5, w5) ACC4(r6, w6) ACC4(r7, w7)
    }
    for (; t < deg; ++t) {
        uint2 q = lp[t];
        uint2 r = *(const uint2*)(hbB + (q.x + cb));
        float wt = __uint_as_float(q.y);
        ACC4(r, wt)
    }

    if (valid) {
        const int c4 = hl << 2;
        float4 bb = *(const float4*)&bias[c4];
        float4 o;
        o.x = fmaxf(a0 + bb.x, 0.f);
        o.y = fmaxf(a1 + bb.y, 0.f);
        o.z = fmaxf(a2 + bb.z, 0.f);
        o.w = fmaxf(a3 + bb.w, 0.f);
        *(float4*)&out[(size_t)d * C + c4] = o;
    }
}

extern "C" void kernel_launch(void* const* d_in, const int* in_sizes, int n_in,
                              void* d_out, int out_size, void* d_ws, size_t ws_size,
                              hipStream_t stream) {
    const float* x     = (const float*)d_in[0];
    const float* W     = (const float*)d_in[1];
    const float* a_src = (const float*)d_in[2];
    const float* a_dst = (const float*)d_in[3];
    const float* bias  = (const float*)d_in[4];
    const int*   edge  = (const int*)d_in[5];

    const int N = in_sizes[0] / C;
    const int E = in_sizes[5] / 2;
    const int total = E + N;
    const int* src = edge;
    const int* dst = edge + E;
    float* out = (float*)d_out;

    const int NB = (N + BKT_MASK) >> BKT_SHIFT;       // 782 buckets (64 nodes)
    const int ntile = (N + 63) / 64;                  // 782 GEMM tiles
    const int chunkE = (total + NB - 1) / NB;         // ~2112 edges/chunk
    const int nG1 = (ntile + 1) / 2;                  // gemm half-1 tiles

    // workspace (4B units): hb[N*C/2] | as[N] | ad[N] | row_start[N+2]
    // | packed[total] | csr[total] | Wf[8192] | wa_s[128] | wa_d[128]
    // | colTot[NBPAD] | bucket_off[NBPAD] | H[NB*NBPAD]
    float* ws = (float*)d_ws;
    unsigned short* hb = (unsigned short*)ws;
    float* as = (float*)(hb + (size_t)N * C);
    float* ad = as + N;
    int* row_start = (int*)(ad + N);
    uint32* packed = (uint32*)(row_start + (N + 2));
    uint32* csr    = packed + total;
    uint32* Wf     = csr + total;
    float* wa_s    = (float*)(Wf + 8192);
    float* wa_d    = wa_s + 128;
    int* colTot    = (int*)(wa_d + 128);
    int* bucket_off = colTot + NBPAD;
    int* H          = bucket_off + NBPAD;

    const int grid1 = (NB > 33) ? NB : 33;
    const int nAlpha = (N + 1023) / 1024;

    cvtw_hist_kernel<<<grid1, 256, 0, stream>>>(
        W, Wf, a_src, a_dst, wa_s, wa_d, dst, H, E, total, NB, chunkE);
    scan_alpha_kernel<<<NB + nAlpha, 1024, 0, stream>>>(
        H, colTot, x, wa_s, wa_d, as, ad, NB, N);
    scan_off_kernel<<<1, 1024, 0, stream>>>(colTot, bucket_off, NB);
    gemm_bin_kernel<<<nG1 + NB, 256, 0, stream>>>(
        x, Wf, hb, N, src, dst, bucket_off, H, packed, E, total, nG1, NB, chunkE);
    build_gemm_kernel<<<NB + (ntile - nG1), 256, 0, stream>>>(
        x, Wf, hb, N, packed, bucket_off, as, ad, row_start, csr, total, nG1, NB);
    gather_kernel<<<((N + 1) / 2 + 3) / 4, 256, 0, stream>>>(csr, row_start, hb, bias, out, N);
}

// Round 14
// 182.881 us; speedup vs baseline: 1.2594x; 1.2594x over previous
//
#include <hip/hip_runtime.h>
#include <hip/hip_fp16.h>

#define C 128
#define NEG_SLOPE 0.2f
#define SM_EPS 1e-16f
#define BKT_SHIFT 8            // 256 nodes per bucket
#define BKT_MASK 255
#define WP 136                 // LDS pitch (u16) for h-writeback slice

typedef unsigned int uint32;
typedef __attribute__((ext_vector_type(8))) short bf16x8;
typedef __attribute__((ext_vector_type(4))) float f32x4;

// ---- bf16 helpers (RNE) ----
static __device__ __forceinline__ unsigned short f2bf(float f) {
    uint32 u = __float_as_uint(f);
    uint32 r = 0x7FFFu + ((u >> 16) & 1u);
    return (unsigned short)((u + r) >> 16);
}
static __device__ __forceinline__ uint32 f2bf2(float lo, float hi) {
    return (uint32)f2bf(lo) | ((uint32)f2bf(hi) << 16);
}
// ---- f16 bit helpers ----
static __device__ __forceinline__ uint32 f2h(float f) {
    __half h = __float2half(f);
    return (uint32)*reinterpret_cast<unsigned short*>(&h);
}
static __device__ __forceinline__ float h2f(uint32 b) {
    unsigned short s = (unsigned short)(b & 0xffffu);
    __half h = *reinterpret_cast<__half*>(&s);
    return __half2float(h);
}

// ---- k1: W -> bf16 fragment-ordered + per-chunk bucket histogram ----
__global__ __launch_bounds__(256) void cvtw_hist_kernel(
    const float* __restrict__ W, uint32* __restrict__ Wf,
    const int* __restrict__ dst, int* __restrict__ H,
    int E, int total, int nchunk, int chunkE)
{
    __shared__ int lhist[256];
    const int tid = threadIdx.x;
    lhist[tid] = 0;
    const int gid = blockIdx.x * 256 + tid;
    if (gid < 8192) {                              // blocks 0..31: W conversion
        int j2   = gid & 3;
        int lane = (gid >> 2) & 63;
        int tile = gid >> 8;                        // t*4+kk
        int t = tile >> 2, kk = tile & 3;
        int n = t * 16 + (lane & 15);
        int k = kk * 32 + (lane >> 4) * 8 + j2 * 2;
        Wf[gid] = f2bf2(W[k * C + n], W[(k + 1) * C + n]);
    }
    const int c = blockIdx.x;
    if (c >= nchunk) return;
    __syncthreads();
    const int start = c * chunkE;
    const int end = min(start + chunkE, total);
    for (int i = start + tid; i < end; i += 256) {
        int d = (i < E) ? dst[i] : (i - E);
        atomicAdd(&lhist[d >> BKT_SHIFT], 1);
    }
    __syncthreads();
    H[c * 256 + tid] = lhist[tid];
}

// ---- k2: parallel column scan of H (one column per block) ----
__global__ __launch_bounds__(1024) void scan_cols_kernel(
    int* __restrict__ H, int* __restrict__ colTot, int nchunk)
{
    __shared__ int wt[16];
    const int tid  = threadIdx.x;
    const int lane = tid & 63;
    const int w    = tid >> 6;
    const int col  = blockIdx.x;
    int v = (tid < nchunk) ? H[tid * 256 + col] : 0;
    int x = v;
    #pragma unroll
    for (int o = 1; o < 64; o <<= 1) {
        int t = __shfl_up(x, o, 64);
        if (lane >= o) x += t;
    }
    if (lane == 63) wt[w] = x;
    __syncthreads();
    int wbase = 0;
    #pragma unroll
    for (int w2 = 0; w2 < 16; ++w2) wbase += (w2 < w) ? wt[w2] : 0;
    int e = wbase + x - v;
    if (tid < nchunk) H[tid * 256 + col] = e;
    if (tid == nchunk - 1) colTot[col] = e + v;
}

// ---- k3: role-split — GEMM tiles (blocks < ntile) || bin chunks (rest) ----
__global__ __launch_bounds__(256) void gemm_bin_kernel(
    const float* __restrict__ x, const uint32* __restrict__ Wf,
    const float* __restrict__ a_src, const float* __restrict__ a_dst,
    unsigned short* __restrict__ hb, float* __restrict__ as_out,
    float* __restrict__ ad_out, int N,
    const int* __restrict__ src, const int* __restrict__ dst,
    const int* __restrict__ colTot, const int* __restrict__ H,
    uint32* __restrict__ packed, int E, int total, int ntile, int chunkE)
{
    __shared__ __align__(16) unsigned short slice[4][16 * WP];
    __shared__ int lhist[256];
    __shared__ int base[256];
    __shared__ int wt[4];

    const int tid  = threadIdx.x;
    const int lane = tid & 63;
    const int w    = tid >> 6;

    if (blockIdx.x < (unsigned)ntile) {
        // ================= GEMM role =================
        const int row0 = blockIdx.x * 64;
        const int m16  = lane & 15;
        const int q    = lane >> 4;

        const int row = row0 + w * 16 + m16;
        const bool rv = (row < N);
        const float* xr_p = x + (size_t)(rv ? row : 0) * C + q * 8;

        float4 xr[8];
        #pragma unroll
        for (int kk = 0; kk < 4; ++kk) {
            xr[kk * 2]     = rv ? *(const float4*)(xr_p + kk * 32)     : make_float4(0, 0, 0, 0);
            xr[kk * 2 + 1] = rv ? *(const float4*)(xr_p + kk * 32 + 4) : make_float4(0, 0, 0, 0);
        }

        f32x4 acc[8];
        const f32x4 zz = {0.f, 0.f, 0.f, 0.f};
        #pragma unroll
        for (int t = 0; t < 8; ++t) acc[t] = zz;

        #pragma unroll
        for (int kk = 0; kk < 4; ++kk) {
            union { bf16x8 v; uint32 u[4]; } au;
            float4 p0 = xr[kk * 2], p1 = xr[kk * 2 + 1];
            au.u[0] = f2bf2(p0.x, p0.y); au.u[1] = f2bf2(p0.z, p0.w);
            au.u[2] = f2bf2(p1.x, p1.y); au.u[3] = f2bf2(p1.z, p1.w);
            #pragma unroll
            for (int t = 0; t < 8; ++t) {
                bf16x8 b = *(const bf16x8*)&Wf[((t * 4 + kk) * 64 + lane) * 4];
                acc[t] = __builtin_amdgcn_mfma_f32_16x16x32_bf16(au.v, b, acc[t], 0, 0, 0);
            }
        }

        float ps[4] = {0.f, 0.f, 0.f, 0.f}, pd[4] = {0.f, 0.f, 0.f, 0.f};
        #pragma unroll
        for (int t = 0; t < 8; ++t) {
            float av = a_src[t * 16 + m16];
            float dv = a_dst[t * 16 + m16];
            #pragma unroll
            for (int r = 0; r < 4; ++r) {
                ps[r] += acc[t][r] * av;
                pd[r] += acc[t][r] * dv;
            }
        }
        #pragma unroll
        for (int r = 0; r < 4; ++r) {
            #pragma unroll
            for (int off = 1; off < 16; off <<= 1) {
                ps[r] += __shfl_xor(ps[r], off, 64);
                pd[r] += __shfl_xor(pd[r], off, 64);
            }
        }
        if (m16 == 0) {
            #pragma unroll
            for (int r = 0; r < 4; ++r) {
                int rr = row0 + w * 16 + q * 4 + r;
                if (rr < N) { as_out[rr] = ps[r]; ad_out[rr] = pd[r]; }
            }
        }

        #pragma unroll
        for (int t = 0; t < 8; ++t)
            #pragma unroll
            for (int r = 0; r < 4; ++r)
                slice[w][(q * 4 + r) * WP + t * 16 + m16] = f2bf(acc[t][r]);
        __syncthreads();
        #pragma unroll
        for (int it = 0; it < 4; ++it) {
            int r = it * 4 + q;
            int rr = row0 + w * 16 + r;
            if (rr < N) {
                bf16x8 v = *(const bf16x8*)&slice[w][r * WP + m16 * 8];
                *(bf16x8*)&hb[(size_t)rr * C + m16 * 8] = v;
            }
        }
    } else {
        // ================= bin role (single-pass deterministic scatter) ====
        const int c = blockIdx.x - ntile;
        const int start = c * chunkE;
        const int end = min(start + chunkE, total);

        // in-block exclusive scan of colTot -> per-bucket global base
        int v = colTot[tid];
        int xx = v;
        #pragma unroll
        for (int o = 1; o < 64; o <<= 1) {
            int t = __shfl_up(xx, o, 64);
            if (lane >= o) xx += t;
        }
        if (lane == 63) wt[w] = xx;
        lhist[tid] = 0;
        __syncthreads();
        int wbase = 0;
        #pragma unroll
        for (int w2 = 0; w2 < 4; ++w2) wbase += (w2 < w) ? wt[w2] : 0;
        base[tid] = (wbase + xx - v) + H[c * 256 + tid];
        __syncthreads();

        for (int i = start + tid; i < end; i += 256) {
            int s = (i < E) ? src[i] : (i - E);
            int d = (i < E) ? dst[i] : (i - E);
            int b = d >> BKT_SHIFT;
            int pos = base[b] + atomicAdd(&lhist[b], 1);
            packed[pos] = ((uint32)s << BKT_SHIFT) | (uint32)(d & BKT_MASK);
        }
    }
}

// ---- k4: build, per-bucket fine sort + fused e (boff from colTot scan) ----
__global__ __launch_bounds__(1024) void build_kernel(
    const uint32* __restrict__ packed, const int* __restrict__ colTot,
    const float* __restrict__ as, const float* __restrict__ ad,
    int* __restrict__ row_start, uint32* __restrict__ csr, int N, int NB, int total)
{
    __shared__ int cnt[256];
    __shared__ int cur[256];
    __shared__ float adl[256];
    __shared__ int wt[4];
    __shared__ int boff[257];
    const int tid = threadIdx.x;
    const int b = blockIdx.x;

    // phase 0: scan colTot -> boff (straight-line barriers, all 1024 thr)
    int v0 = 0, x0 = 0;
    if (tid < 256) {
        const int lane = tid & 63;
        v0 = colTot[tid]; x0 = v0;
        #pragma unroll
        for (int o = 1; o < 64; o <<= 1) {
            int t = __shfl_up(x0, o, 64);
            if (lane >= o) x0 += t;
        }
        if (lane == 63) wt[tid >> 6] = x0;
        cnt[tid] = 0;
        int g = (b << BKT_SHIFT) + tid;
        adl[tid] = (g < N) ? ad[g] : 0.f;
    }
    __syncthreads();
    if (tid < 256) {
        const int w = tid >> 6;
        int wbase = 0;
        #pragma unroll
        for (int w2 = 0; w2 < 4; ++w2) wbase += (w2 < w) ? wt[w2] : 0;
        boff[tid] = wbase + x0 - v0;
        if (tid == 0) boff[256] = total;
    }
    __syncthreads();

    const int off = boff[b];
    const int end = boff[b + 1];
    if (b == 0 && tid == 0) row_start[N] = total;

    for (int j = off + tid; j < end; j += 1024)
        atomicAdd(&cnt[packed[j] & BKT_MASK], 1);
    __syncthreads();

    int v2 = 0, x2 = 0;
    if (tid < 256) {
        const int lane = tid & 63;
        v2 = cnt[tid]; x2 = v2;
        #pragma unroll
        for (int o = 1; o < 64; o <<= 1) {
            int t = __shfl_up(x2, o, 64);
            if (lane >= o) x2 += t;
        }
        if (lane == 63) wt[tid >> 6] = x2;
    }
    __syncthreads();
    if (tid < 256) {
        const int w = tid >> 6;
        int wbase = 0;
        #pragma unroll
        for (int w2 = 0; w2 < 4; ++w2) wbase += (w2 < w) ? wt[w2] : 0;
        int excl = wbase + x2 - v2;
        int g = (b << BKT_SHIFT) + tid;
        if (g < N) row_start[g] = off + excl;
        cur[tid] = excl;
    }
    __syncthreads();

    for (int j = off + tid; j < end; j += 1024) {
        uint32 p = packed[j];
        int l = (int)(p & BKT_MASK);
        int s = (int)(p >> BKT_SHIFT);
        float e = as[s] + adl[l];
        e = (e > 0.f) ? e : NEG_SLOPE * e;
        int pos = atomicAdd(&cur[l], 1);
        csr[off + pos] = ((uint32)s << 16) | f2h(e);
    }
}

// ---- full-wave fallback for deg>64 nodes ----
static __device__ __forceinline__ void gather_node_fw(
    int d, const uint32* __restrict__ csr, const int* __restrict__ row_start,
    const unsigned short* __restrict__ hb, const float* __restrict__ bias,
    float* __restrict__ out, int lane)
{
    const int beg = row_start[d];
    const int deg = row_start[d + 1] - beg;
    const int c2 = lane << 1;
    float a0 = 0.f, a1 = 0.f;
    float m = -INFINITY;
    for (int t = lane; t < deg; t += 64) m = fmaxf(m, h2f(csr[beg + t]));
    #pragma unroll
    for (int off = 32; off > 0; off >>= 1) m = fmaxf(m, __shfl_xor(m, off, 64));
    float ssum = 0.f;
    for (int t = lane; t < deg; t += 64) ssum += __expf(h2f(csr[beg + t]) - m);
    #pragma unroll
    for (int off = 32; off > 0; off >>= 1) ssum += __shfl_xor(ssum, off, 64);
    float inv = 1.f / (ssum + SM_EPS);
    for (int t0 = 0; t0 < deg; t0 += 64) {
        int nc = min(64, deg - t0);
        uint32 ent = (lane < nc) ? csr[beg + t0 + lane] : 0xFC00u;
        float wl = (lane < nc) ? __expf(h2f(ent) - m) * inv : 0.f;
        uint32 bc = (ent & 0xffff0000u) | f2h(wl);
        for (int t = 0; t < nc; ++t) {
            uint32 b0 = (uint32)__shfl((int)bc, t, 64);
            uint32 u0 = *(const uint32*)&hb[(size_t)(b0 >> 16) * C + c2];
            float w0 = h2f(b0);
            a0 += __uint_as_float(u0 << 16) * w0;
            a1 += __uint_as_float(u0 & 0xffff0000u) * w0;
        }
    }
    float2 b2 = *(const float2*)&bias[c2];
    a0 = fmaxf(a0 + b2.x, 0.f);
    a1 = fmaxf(a1 + b2.y, 0.f);
    *(float2*)&out[(size_t)d * C + c2] = make_float2(a0, a1);
}

// per-edge unpack+FMA on a loaded uint2 row fragment (4 bf16 channels)
#define ACC4(r, wgt)                                           \
    {                                                          \
        a0 += __uint_as_float((r).x << 16)         * (wgt);    \
        a1 += __uint_as_float((r).x & 0xffff0000u) * (wgt);    \
        a2 += __uint_as_float((r).y << 16)         * (wgt);    \
        a3 += __uint_as_float((r).y & 0xffff0000u) * (wgt);    \
    }

// ---- k5: half-wave gather: 2 dst nodes per wave, 4 ch/lane, MLP=8 ----
__global__ __launch_bounds__(256) void gather_kernel(
    const uint32* __restrict__ csr, const int* __restrict__ row_start,
    const unsigned short* __restrict__ hb, const float* __restrict__ bias,
    float* __restrict__ out, int N)
{
    __shared__ __align__(16) uint2 lent[4][2][64];   // 4 KB: per-wave, per-half
    const int w    = threadIdx.x >> 6;
    const int lane = threadIdx.x & 63;
    const int half = lane >> 5;
    const int hl   = lane & 31;
    const int pair = blockIdx.x * 4 + w;
    const int d0 = pair * 2;
    if (d0 >= N) return;                    // no barriers below: safe
    const int d = d0 + half;
    const bool valid = (d < N);

    int beg = 0, deg = 0;
    if (valid) { beg = row_start[d]; deg = row_start[d + 1] - beg; }

    int wdeg = deg;
    #pragma unroll
    for (int off = 32; off > 0; off >>= 1) wdeg = max(wdeg, __shfl_xor(wdeg, off, 64));

    if (wdeg > 64) {
        gather_node_fw(d0, csr, row_start, hb, bias, out, lane);
        if (d0 + 1 < N) gather_node_fw(d0 + 1, csr, row_start, hb, bias, out, lane);
        return;
    }

    uint32 ent0 = (hl < deg) ? csr[beg + hl] : 0xFC00u;
    uint32 ent1 = (32 + hl < deg) ? csr[beg + 32 + hl] : 0xFC00u;
    float e0 = h2f(ent0), e1 = h2f(ent1);
    float m = fmaxf(e0, e1);
    #pragma unroll
    for (int off = 16; off > 0; off >>= 1) m = fmaxf(m, __shfl_xor(m, off, 64));
    float p0 = (hl < deg) ? __expf(e0 - m) : 0.f;
    float p1 = (32 + hl < deg) ? __expf(e1 - m) : 0.f;
    float ssum = p0 + p1;
    #pragma unroll
    for (int off = 16; off > 0; off >>= 1) ssum += __shfl_xor(ssum, off, 64);
    const float inv = 1.f / (ssum + SM_EPS);

    // stage {row byte offset = src*256, f32 weight} — wave-synchronous LDS
    lent[w][half][hl]      = make_uint2((ent0 & 0xffff0000u) >> 8, __float_as_uint(p0 * inv));
    lent[w][half][32 + hl] = make_uint2((ent1 & 0xffff0000u) >> 8, __float_as_uint(p1 * inv));
    __builtin_amdgcn_wave_barrier();        // keep writes before reads (same wave)

    const uint32 cb = (uint32)(hl << 3);    // this lane's channel byte offset
    const char* hbB = (const char*)hb;
    const uint2* lp = &lent[w][half][0];
    float a0 = 0.f, a1 = 0.f, a2 = 0.f, a3 = 0.f;

    int t = 0;
    for (; t + 8 <= deg; t += 8) {
        uint4 q0 = *(const uint4*)(lp + t);
        uint4 q1 = *(const uint4*)(lp + t + 2);
        uint4 q2 = *(const uint4*)(lp + t + 4);
        uint4 q3 = *(const uint4*)(lp + t + 6);
        uint2 r0 = *(const uint2*)(hbB + (q0.x + cb));
        uint2 r1 = *(const uint2*)(hbB + (q0.z + cb));
        uint2 r2 = *(const uint2*)(hbB + (q1.x + cb));
        uint2 r3 = *(const uint2*)(hbB + (q1.z + cb));
        uint2 r4 = *(const uint2*)(hbB + (q2.x + cb));
        uint2 r5 = *(const uint2*)(hbB + (q2.z + cb));
        uint2 r6 = *(const uint2*)(hbB + (q3.x + cb));
        uint2 r7 = *(const uint2*)(hbB + (q3.z + cb));
        float w0 = __uint_as_float(q0.y), w1 = __uint_as_float(q0.w);
        float w2 = __uint_as_float(q1.y), w3 = __uint_as_float(q1.w);
        float w4 = __uint_as_float(q2.y), w5 = __uint_as_float(q2.w);
        float w6 = __uint_as_float(q3.y), w7 = __uint_as_float(q3.w);
        ACC4(r0, w0) ACC4(r1, w1) ACC4(r2, w2) ACC4(r3, w3)
        ACC4(r4, w4) ACC4(r5, w5) ACC4(r6, w6) ACC4(r7, w7)
    }
    for (; t < deg; ++t) {
        uint2 q = lp[t];
        uint2 r = *(const uint2*)(hbB + (q.x + cb));
        float wt = __uint_as_float(q.y);
        ACC4(r, wt)
    }

    if (valid) {
        const int c4 = hl << 2;
        float4 bb = *(const float4*)&bias[c4];
        float4 o;
        o.x = fmaxf(a0 + bb.x, 0.f);
        o.y = fmaxf(a1 + bb.y, 0.f);
        o.z = fmaxf(a2 + bb.z, 0.f);
        o.w = fmaxf(a3 + bb.w, 0.f);
        *(float4*)&out[(size_t)d * C + c4] = o;
    }
}

extern "C" void kernel_launch(void* const* d_in, const int* in_sizes, int n_in,
                              void* d_out, int out_size, void* d_ws, size_t ws_size,
                              hipStream_t stream) {
    const float* x     = (const float*)d_in[0];
    const float* W     = (const float*)d_in[1];
    const float* a_src = (const float*)d_in[2];
    const float* a_dst = (const float*)d_in[3];
    const float* bias  = (const float*)d_in[4];
    const int*   edge  = (const int*)d_in[5];

    const int N = in_sizes[0] / C;
    const int E = in_sizes[5] / 2;
    const int total = E + N;
    const int* src = edge;
    const int* dst = edge + E;
    float* out = (float*)d_out;

    const int NB = (N + BKT_MASK) >> BKT_SHIFT;       // 196 buckets
    const int ntile = (N + 63) / 64;                  // 782 (= nchunk)
    const int chunkE = (total + ntile - 1) / ntile;   // ~2112 edges/chunk

    // workspace (4B units): hb[N*C/2] | as[N] | ad[N] | row_start[N+2]
    // | packed[total] | csr[total] | Wf[8192] | colTot[256] | H[ntile*256]
    float* ws = (float*)d_ws;
    unsigned short* hb = (unsigned short*)ws;
    float* as = (float*)(hb + (size_t)N * C);
    float* ad = as + N;
    int* row_start = (int*)(ad + N);
    uint32* packed = (uint32*)(row_start + (N + 2));
    uint32* csr    = packed + total;
    uint32* Wf     = csr + total;
    int* colTot    = (int*)(Wf + 8192);
    int* H         = colTot + 256;

    const int grid1 = (ntile > 32) ? ntile : 32;

    cvtw_hist_kernel<<<grid1, 256, 0, stream>>>(W, Wf, dst, H, E, total, ntile, chunkE);
    scan_cols_kernel<<<256, 1024, 0, stream>>>(H, colTot, ntile);
    gemm_bin_kernel<<<2 * ntile, 256, 0, stream>>>(
        x, Wf, a_src, a_dst, hb, as, ad, N, src, dst,
        colTot, H, packed, E, total, ntile, chunkE);
    build_kernel<<<NB, 1024, 0, stream>>>(packed, colTot, as, ad, row_start,
                                          csr, N, NB, total);
    gather_kernel<<<((N + 1) / 2 + 3) / 4, 256, 0, stream>>>(csr, row_start, hb, bias, out, N);
}